// Round 5
// baseline (36.771 us; speedup 1.0000x reference)
//
#include <hip/hip_runtime.h>

// Problem constants (RES = 64)
#define RES       64
#define CM1       63
#define NCELL     250047      // 63^3
#define NTET      1500282     // NCELL*6
#define V_ELEMS   27005076    // NTET*18  (v_pos: 6 edges * 3 coords per tet, float32)
#define TRI_ELEMS 9001692     // NTET*6   (2 tris * 3 idx per tet, stored as float32)
// valid: NTET*2 float32 elements follow tri

#define TPB 256

typedef float f32x4 __attribute__((ext_vector_type(4)));  // clang vector: valid for nontemporal builtins

__constant__ int c_TETS[6][4] = {
    {0,5,1,6},{0,1,2,6},{0,2,3,6},{0,3,7,6},{0,7,4,6},{0,4,5,6}
};
__constant__ int c_OFF[8][3] = {
    {0,0,0},{1,0,0},{1,1,0},{0,1,0},{0,0,1},{1,0,1},{1,1,1},{0,1,1}
};
// TET_TRIS[16][2][3] flattened; -1 = invalid
__constant__ int c_TRI[16][6] = {
    {-1,-1,-1,-1,-1,-1},  // 0
    { 0, 3, 2,-1,-1,-1},  // 1
    { 0, 1, 4,-1,-1,-1},  // 2
    { 2, 3, 4, 2, 4, 1},  // 3
    { 1, 5, 2,-1,-1,-1},  // 4
    { 0, 1, 5, 0, 5, 3},  // 5
    { 0, 4, 5, 0, 5, 2},  // 6
    { 3, 4, 5,-1,-1,-1},  // 7
    { 3, 5, 4,-1,-1,-1},  // 8
    { 0, 2, 5, 0, 5, 4},  // 9
    { 0, 3, 5, 0, 5, 1},  // 10
    { 1, 2, 5,-1,-1,-1},  // 11
    { 1, 4, 3, 1, 3, 2},  // 12
    { 0, 4, 1,-1,-1,-1},  // 13
    { 0, 2, 3,-1,-1,-1},  // 14
    {-1,-1,-1,-1,-1,-1}   // 15
};

__device__ __forceinline__ void nt_store(f32x4* p, f32x4 v) {
    __builtin_nontemporal_store(v, p);   // global_store_dwordx4 ... nt (skip L2 alloc)
}

__global__ __launch_bounds__(TPB) void mc_kernel(const float* __restrict__ level,
                                                 float* __restrict__ out)
{
    // LDS staging buffers laid out exactly like the per-block global regions.
    __shared__ float sv[TPB * 18];  // v_pos   18 KiB
    __shared__ float st[TPB * 6];   // tri      6 KiB
    __shared__ float sl[TPB * 2];   // valid    2 KiB

    int t  = threadIdx.x;
    int g0 = blockIdx.x * TPB;
    int g  = g0 + t;
    int ntet = NTET - g0; if (ntet > TPB) ntet = TPB;   // 256, or 122 in the tail block

    if (t < ntet) {
        int cell = g / 6;
        int tet  = g - cell * 6;
        int i    = cell / (CM1 * CM1);
        int rem  = cell - i * (CM1 * CM1);
        int j    = rem / CM1;
        int k    = rem - j * CM1;
        int base = i * (RES * RES) + j * RES + k;

        // Gather the 4 tet corners: f = -level, positions = (i,j,k)+offset
        float fv[4], px[4], py[4], pz[4];
        #pragma unroll
        for (int vi = 0; vi < 4; ++vi) {
            int c  = c_TETS[tet][vi];
            int ox = c_OFF[c][0], oy = c_OFF[c][1], oz = c_OFF[c][2];
            fv[vi] = -level[base + ox * (RES * RES) + oy * RES + oz];
            px[vi] = (float)(i + ox);
            py[vi] = (float)(j + oy);
            pz[vi] = (float)(k + oz);
        }

        int cs = (fv[0] > 0.0f ? 1 : 0) | (fv[1] > 0.0f ? 2 : 0)
               | (fv[2] > 0.0f ? 4 : 0) | (fv[3] > 0.0f ? 8 : 0);

        const int EA[6] = {0, 1, 2, 0, 1, 2};
        const int EB[6] = {1, 2, 0, 3, 3, 3};

        const float inv63 = 1.0f / 63.0f;
        #pragma unroll
        for (int e = 0; e < 6; ++e) {
            int a = EA[e], b = EB[e];
            float fa = fv[a], fb = fv[b];
            float d  = fa - fb;
            float ds = (fabsf(d) < 1e-8f) ? 1e-8f : d;
            float tt = fa / ds;                       // IEEE f32 divide, matches np
            tt = fminf(fmaxf(tt, 0.0f), 1.0f);
            float vx = px[a] + tt * (px[b] - px[a]);
            float vy = py[a] + tt * (py[b] - py[a]);
            float vz = pz[a] + tt * (pz[b] - pz[a]);
            // reference reverses coord order: (z, y, x) / 63
            sv[t * 18 + e * 3 + 0] = vz * inv63;     // stride 18 -> 2-way bank alias (free)
            sv[t * 18 + e * 3 + 1] = vy * inv63;
            sv[t * 18 + e * 3 + 2] = vx * inv63;
        }

        int base6 = g * 6;
        #pragma unroll
        for (int tr = 0; tr < 2; ++tr) {
            int t0 = c_TRI[cs][tr * 3 + 0];
            int t1 = c_TRI[cs][tr * 3 + 1];
            int t2 = c_TRI[cs][tr * 3 + 2];
            sl[t * 2 + tr] = (t0 >= 0) ? 1.0f : 0.0f;
            int m0 = t0 > 0 ? t0 : 0;
            int m1 = t1 > 0 ? t1 : 0;
            int m2 = t2 > 0 ? t2 : 0;
            st[t * 6 + tr * 3 + 0] = (float)(base6 + m0);  // < 2^24, exact in f32
            st[t * 6 + tr * 3 + 1] = (float)(base6 + m1);
            st[t * 6 + tr * 3 + 2] = (float)(base6 + m2);
        }
    }

    __syncthreads();

    // Coalesced nontemporal f32x4 copy-out (write-once data: skip L2 allocation).
    if (ntet == TPB) {
        // Full block: compile-time trip counts, fully unrolled.
        f32x4*       gv = (f32x4*)(out + (size_t)g0 * 18);
        const f32x4* lv = (const f32x4*)sv;
        #pragma unroll
        for (int n = 0; n < 4; ++n)                       // 4*256 = 1024 of 1152
            nt_store(&gv[t + n * TPB], lv[t + n * TPB]);
        if (t < 128) nt_store(&gv[t + 4 * TPB], lv[t + 4 * TPB]);  // last 128

        f32x4*       gt = (f32x4*)(out + V_ELEMS + (size_t)g0 * 6);
        const f32x4* lt = (const f32x4*)st;
        nt_store(&gt[t], lt[t]);                          // 256 of 384
        if (t < 128) nt_store(&gt[t + TPB], lt[t + TPB]);

        f32x4*       gl = (f32x4*)(out + V_ELEMS + TRI_ELEMS + (size_t)g0 * 2);
        const f32x4* ll = (const f32x4*)sl;
        if (t < 128) nt_store(&gl[t], ll[t]);             // 128
    } else {
        // Tail block (122 tets): generic strided loops.
        {
            int n4 = (ntet * 18) >> 2;
            f32x4*       gv = (f32x4*)(out + (size_t)g0 * 18);
            const f32x4* lv = (const f32x4*)sv;
            for (int idx = t; idx < n4; idx += TPB) nt_store(&gv[idx], lv[idx]);
        }
        {
            int n4 = (ntet * 6) >> 2;
            f32x4*       gt = (f32x4*)(out + V_ELEMS + (size_t)g0 * 6);
            const f32x4* lt = (const f32x4*)st;
            for (int idx = t; idx < n4; idx += TPB) nt_store(&gt[idx], lt[idx]);
        }
        {
            int n4 = (ntet * 2) >> 2;
            f32x4*       gl = (f32x4*)(out + V_ELEMS + TRI_ELEMS + (size_t)g0 * 2);
            const f32x4* ll = (const f32x4*)sl;
            for (int idx = t; idx < n4; idx += TPB) nt_store(&gl[idx], ll[idx]);
        }
    }
}

extern "C" void kernel_launch(void* const* d_in, const int* in_sizes, int n_in,
                              void* d_out, int out_size, void* d_ws, size_t ws_size,
                              hipStream_t stream) {
    const float* level = (const float*)d_in[0];
    float* out = (float*)d_out;
    int blocks = (NTET + TPB - 1) / TPB;
    mc_kernel<<<blocks, TPB, 0, stream>>>(level, out);
}

// Round 6
// 31.167 us; speedup vs baseline: 1.1798x; 1.1798x over previous
//
#include <hip/hip_runtime.h>

// Problem constants (RES = 64)
#define RES       64
#define CM1       63
#define NCELL     250047      // 63^3
#define NTET      1500282     // NCELL*6
#define V_ELEMS   27005076    // NTET*18  (v_pos: 6 edges * 3 coords per tet, float32)
#define TRI_ELEMS 9001692     // NTET*6   (2 tris * 3 idx per tet, stored as float32)
// valid: NTET*2 float32 elements follow tri

#define TPB 512   // 8 waves/block, 53 KB LDS -> 3 blocks/CU (24 waves), longer store streams

__constant__ int c_TETS[6][4] = {
    {0,5,1,6},{0,1,2,6},{0,2,3,6},{0,3,7,6},{0,7,4,6},{0,4,5,6}
};
__constant__ int c_OFF[8][3] = {
    {0,0,0},{1,0,0},{1,1,0},{0,1,0},{0,0,1},{1,0,1},{1,1,1},{0,1,1}
};
// TET_TRIS[16][2][3] flattened; -1 = invalid
__constant__ int c_TRI[16][6] = {
    {-1,-1,-1,-1,-1,-1},  // 0
    { 0, 3, 2,-1,-1,-1},  // 1
    { 0, 1, 4,-1,-1,-1},  // 2
    { 2, 3, 4, 2, 4, 1},  // 3
    { 1, 5, 2,-1,-1,-1},  // 4
    { 0, 1, 5, 0, 5, 3},  // 5
    { 0, 4, 5, 0, 5, 2},  // 6
    { 3, 4, 5,-1,-1,-1},  // 7
    { 3, 5, 4,-1,-1,-1},  // 8
    { 0, 2, 5, 0, 5, 4},  // 9
    { 0, 3, 5, 0, 5, 1},  // 10
    { 1, 2, 5,-1,-1,-1},  // 11
    { 1, 4, 3, 1, 3, 2},  // 12
    { 0, 4, 1,-1,-1,-1},  // 13
    { 0, 2, 3,-1,-1,-1},  // 14
    {-1,-1,-1,-1,-1,-1}   // 15
};

__global__ __launch_bounds__(TPB) void mc_kernel(const float* __restrict__ level,
                                                 float* __restrict__ out)
{
    // LDS staging buffers laid out exactly like the per-block global regions.
    __shared__ float sv[TPB * 18];  // v_pos   36 KiB
    __shared__ float st[TPB * 6];   // tri     12 KiB
    __shared__ float sl[TPB * 2];   // valid    4 KiB

    int t  = threadIdx.x;
    int g0 = blockIdx.x * TPB;
    int g  = g0 + t;
    int ntet = NTET - g0; if (ntet > TPB) ntet = TPB;   // 512, or 122 in the tail block

    if (t < ntet) {
        int cell = g / 6;
        int tet  = g - cell * 6;
        int i    = cell / (CM1 * CM1);
        int rem  = cell - i * (CM1 * CM1);
        int j    = rem / CM1;
        int k    = rem - j * CM1;
        int base = i * (RES * RES) + j * RES + k;

        // Gather the 4 tet corners: f = -level, positions = (i,j,k)+offset
        float fv[4], px[4], py[4], pz[4];
        #pragma unroll
        for (int vi = 0; vi < 4; ++vi) {
            int c  = c_TETS[tet][vi];
            int ox = c_OFF[c][0], oy = c_OFF[c][1], oz = c_OFF[c][2];
            fv[vi] = -level[base + ox * (RES * RES) + oy * RES + oz];
            px[vi] = (float)(i + ox);
            py[vi] = (float)(j + oy);
            pz[vi] = (float)(k + oz);
        }

        int cs = (fv[0] > 0.0f ? 1 : 0) | (fv[1] > 0.0f ? 2 : 0)
               | (fv[2] > 0.0f ? 4 : 0) | (fv[3] > 0.0f ? 8 : 0);

        const int EA[6] = {0, 1, 2, 0, 1, 2};
        const int EB[6] = {1, 2, 0, 3, 3, 3};

        const float inv63 = 1.0f / 63.0f;
        #pragma unroll
        for (int e = 0; e < 6; ++e) {
            int a = EA[e], b = EB[e];
            float fa = fv[a], fb = fv[b];
            float d  = fa - fb;
            float ds = (fabsf(d) < 1e-8f) ? 1e-8f : d;
            float tt = fa / ds;                       // IEEE f32 divide, matches np
            tt = fminf(fmaxf(tt, 0.0f), 1.0f);
            float vx = px[a] + tt * (px[b] - px[a]);
            float vy = py[a] + tt * (py[b] - py[a]);
            float vz = pz[a] + tt * (pz[b] - pz[a]);
            // reference reverses coord order: (z, y, x) / 63
            sv[t * 18 + e * 3 + 0] = vz * inv63;     // stride 18 -> 2-way bank alias (free)
            sv[t * 18 + e * 3 + 1] = vy * inv63;
            sv[t * 18 + e * 3 + 2] = vx * inv63;
        }

        int base6 = g * 6;
        #pragma unroll
        for (int tr = 0; tr < 2; ++tr) {
            int t0 = c_TRI[cs][tr * 3 + 0];
            int t1 = c_TRI[cs][tr * 3 + 1];
            int t2 = c_TRI[cs][tr * 3 + 2];
            sl[t * 2 + tr] = (t0 >= 0) ? 1.0f : 0.0f;
            int m0 = t0 > 0 ? t0 : 0;
            int m1 = t1 > 0 ? t1 : 0;
            int m2 = t2 > 0 ? t2 : 0;
            st[t * 6 + tr * 3 + 0] = (float)(base6 + m0);  // < 2^24, exact in f32
            st[t * 6 + tr * 3 + 1] = (float)(base6 + m1);
            st[t * 6 + tr * 3 + 2] = (float)(base6 + m2);
        }
    }

    __syncthreads();

    // Coalesced float4 copy-out (plain stores: L2 write-back coalesces; nt regressed).
    if (ntet == TPB) {
        // Full block: compile-time trip counts, fully unrolled.
        float4*       gv = (float4*)(out + (size_t)g0 * 18);
        const float4* lv = (const float4*)sv;
        #pragma unroll
        for (int n = 0; n < 4; ++n)                       // 4*512 = 2048 of 2304
            gv[t + n * TPB] = lv[t + n * TPB];
        if (t < TPB / 2) gv[t + 4 * TPB] = lv[t + 4 * TPB];  // last 256

        float4*       gt = (float4*)(out + V_ELEMS + (size_t)g0 * 6);
        const float4* lt = (const float4*)st;
        gt[t] = lt[t];                                    // 512 of 768
        if (t < TPB / 2) gt[t + TPB] = lt[t + TPB];

        float4*       gl = (float4*)(out + V_ELEMS + TRI_ELEMS + (size_t)g0 * 2);
        const float4* ll = (const float4*)sl;
        if (t < TPB / 2) gl[t] = ll[t];                   // 256
    } else {
        // Tail block (122 tets): generic strided loops.
        {
            int n4 = (ntet * 18) >> 2;
            float4*       gv = (float4*)(out + (size_t)g0 * 18);
            const float4* lv = (const float4*)sv;
            for (int idx = t; idx < n4; idx += TPB) gv[idx] = lv[idx];
        }
        {
            int n4 = (ntet * 6) >> 2;
            float4*       gt = (float4*)(out + V_ELEMS + (size_t)g0 * 6);
            const float4* lt = (const float4*)st;
            for (int idx = t; idx < n4; idx += TPB) gt[idx] = lt[idx];
        }
        {
            int n4 = (ntet * 2) >> 2;
            float4*       gl = (float4*)(out + V_ELEMS + TRI_ELEMS + (size_t)g0 * 2);
            const float4* ll = (const float4*)sl;
            for (int idx = t; idx < n4; idx += TPB) gl[idx] = ll[idx];
        }
    }
}

extern "C" void kernel_launch(void* const* d_in, const int* in_sizes, int n_in,
                              void* d_out, int out_size, void* d_ws, size_t ws_size,
                              hipStream_t stream) {
    const float* level = (const float*)d_in[0];
    float* out = (float*)d_out;
    int blocks = (NTET + TPB - 1) / TPB;
    mc_kernel<<<blocks, TPB, 0, stream>>>(level, out);
}

// Round 7
// 30.915 us; speedup vs baseline: 1.1894x; 1.0082x over previous
//
#include <hip/hip_runtime.h>

// Problem constants (RES = 64)
#define RES       64
#define CM1       63
#define NCELL     250047      // 63^3
#define NTET      1500282     // NCELL*6
#define V_ELEMS   27005076    // NTET*18  (v_pos: 6 edges * 3 coords per tet, float32)
#define TRI_ELEMS 9001692     // NTET*6   (2 tris * 3 idx per tet, stored as float32)
// valid: NTET*2 float32 elements follow tri

#define TPB 256   // 4 waves/block, 26.6 KB LDS -> 6 blocks/CU (24 waves)

__constant__ int c_TETS[6][4] = {
    {0,5,1,6},{0,1,2,6},{0,2,3,6},{0,3,7,6},{0,7,4,6},{0,4,5,6}
};
__constant__ int c_OFF[8][3] = {
    {0,0,0},{1,0,0},{1,1,0},{0,1,0},{0,0,1},{1,0,1},{1,1,1},{0,1,1}
};
// TET_TRIS[16][2][3] flattened; -1 = invalid
__constant__ int c_TRI[16][6] = {
    {-1,-1,-1,-1,-1,-1},  // 0
    { 0, 3, 2,-1,-1,-1},  // 1
    { 0, 1, 4,-1,-1,-1},  // 2
    { 2, 3, 4, 2, 4, 1},  // 3
    { 1, 5, 2,-1,-1,-1},  // 4
    { 0, 1, 5, 0, 5, 3},  // 5
    { 0, 4, 5, 0, 5, 2},  // 6
    { 3, 4, 5,-1,-1,-1},  // 7
    { 3, 5, 4,-1,-1,-1},  // 8
    { 0, 2, 5, 0, 5, 4},  // 9
    { 0, 3, 5, 0, 5, 1},  // 10
    { 1, 2, 5,-1,-1,-1},  // 11
    { 1, 4, 3, 1, 3, 2},  // 12
    { 0, 4, 1,-1,-1,-1},  // 13
    { 0, 2, 3,-1,-1,-1},  // 14
    {-1,-1,-1,-1,-1,-1}   // 15
};

__global__ __launch_bounds__(TPB) void mc_kernel(const float* __restrict__ level,
                                                 float* __restrict__ out)
{
    // Per-wave-private LDS staging: wave w only touches tet slots [w*64, w*64+64).
    __shared__ float sv[TPB * 18];  // v_pos   18 KiB
    __shared__ float st[TPB * 6];   // tri      6 KiB
    __shared__ float sl[TPB * 2];   // valid    2 KiB

    int t  = threadIdx.x;
    int w  = t >> 6;                 // wave id within block
    int l  = t & 63;                 // lane
    int g0 = blockIdx.x * TPB;
    int g  = g0 + t;
    int ntet = NTET - g0; if (ntet > TPB) ntet = TPB;   // 256, or 122 in the tail block
    int ntw = ntet - w * 64;                            // tets owned by this wave
    ntw = ntw < 0 ? 0 : (ntw > 64 ? 64 : ntw);          // always even

    if (l < ntw) {
        int cell = g / 6;
        int tet  = g - cell * 6;
        int i    = cell / (CM1 * CM1);
        int rem  = cell - i * (CM1 * CM1);
        int j    = rem / CM1;
        int k    = rem - j * CM1;
        int base = i * (RES * RES) + j * RES + k;

        // Gather the 4 tet corners: f = -level, positions = (i,j,k)+offset
        float fv[4], px[4], py[4], pz[4];
        #pragma unroll
        for (int vi = 0; vi < 4; ++vi) {
            int c  = c_TETS[tet][vi];
            int ox = c_OFF[c][0], oy = c_OFF[c][1], oz = c_OFF[c][2];
            fv[vi] = -level[base + ox * (RES * RES) + oy * RES + oz];
            px[vi] = (float)(i + ox);
            py[vi] = (float)(j + oy);
            pz[vi] = (float)(k + oz);
        }

        int cs = (fv[0] > 0.0f ? 1 : 0) | (fv[1] > 0.0f ? 2 : 0)
               | (fv[2] > 0.0f ? 4 : 0) | (fv[3] > 0.0f ? 8 : 0);

        const int EA[6] = {0, 1, 2, 0, 1, 2};
        const int EB[6] = {1, 2, 0, 3, 3, 3};

        const float inv63 = 1.0f / 63.0f;
        #pragma unroll
        for (int e = 0; e < 6; ++e) {
            int a = EA[e], b = EB[e];
            float fa = fv[a], fb = fv[b];
            float d  = fa - fb;
            float ds = (fabsf(d) < 1e-8f) ? 1e-8f : d;
            // fast reciprocal instead of IEEE divide chain: ~1 ulp on the trans pipe,
            // far under the bf16-quantized 2% threshold; clamp handles inf identically.
            float tt = fa * __builtin_amdgcn_rcpf(ds);
            tt = fminf(fmaxf(tt, 0.0f), 1.0f);
            float vx = px[a] + tt * (px[b] - px[a]);
            float vy = py[a] + tt * (py[b] - py[a]);
            float vz = pz[a] + tt * (pz[b] - pz[a]);
            // reference reverses coord order: (z, y, x) / 63
            sv[t * 18 + e * 3 + 0] = vz * inv63;     // stride 18 -> 2-way bank alias (free)
            sv[t * 18 + e * 3 + 1] = vy * inv63;
            sv[t * 18 + e * 3 + 2] = vx * inv63;
        }

        int base6 = g * 6;
        #pragma unroll
        for (int tr = 0; tr < 2; ++tr) {
            int t0 = c_TRI[cs][tr * 3 + 0];
            int t1 = c_TRI[cs][tr * 3 + 1];
            int t2 = c_TRI[cs][tr * 3 + 2];
            sl[t * 2 + tr] = (t0 >= 0) ? 1.0f : 0.0f;
            int m0 = t0 > 0 ? t0 : 0;
            int m1 = t1 > 0 ? t1 : 0;
            int m2 = t2 > 0 ? t2 : 0;
            st[t * 6 + tr * 3 + 0] = (float)(base6 + m0);  // < 2^24, exact in f32
            st[t * 6 + tr * 3 + 1] = (float)(base6 + m1);
            st[t * 6 + tr * 3 + 2] = (float)(base6 + m2);
        }
    }

    // NO __syncthreads(): each wave reads back only its own LDS slice.
    // DS ops within a wave complete in order; this fence stops compiler reordering.
    __builtin_amdgcn_wave_barrier();

    // Per-wave coalesced float4 copy-out of this wave's own slice.
    if (ntw == 64) {
        // v_pos: 64*18 = 1152 floats = 288 float4 (4.5 per lane), unrolled
        float4*       gv = (float4*)(out + (size_t)g0 * 18) + (size_t)w * 288;
        const float4* lv = (const float4*)sv + w * 288;
        #pragma unroll
        for (int n = 0; n < 4; ++n) gv[l + n * 64] = lv[l + n * 64];
        if (l < 32) gv[l + 256] = lv[l + 256];

        // tri: 64*6 = 384 floats = 96 float4 (1.5 per lane)
        float4*       gt = (float4*)(out + V_ELEMS + (size_t)g0 * 6) + (size_t)w * 96;
        const float4* lt = (const float4*)st + w * 96;
        gt[l] = lt[l];
        if (l < 32) gt[l + 64] = lt[l + 64];

        // valid: 64*2 = 128 floats = 32 float4
        float4*       gl = (float4*)(out + V_ELEMS + TRI_ELEMS + (size_t)g0 * 2) + (size_t)w * 32;
        const float4* ll = (const float4*)sl + w * 32;
        if (l < 32) gl[l] = ll[l];
    } else if (ntw > 0) {
        // Tail wave (ntw even): generic per-wave strided loops.
        int n4v = (ntw * 18) >> 2;
        float4*       gv = (float4*)(out + (size_t)g0 * 18) + (size_t)w * 288;
        const float4* lv = (const float4*)sv + w * 288;
        for (int idx = l; idx < n4v; idx += 64) gv[idx] = lv[idx];

        int n4t = (ntw * 6) >> 2;
        float4*       gt = (float4*)(out + V_ELEMS + (size_t)g0 * 6) + (size_t)w * 96;
        const float4* lt = (const float4*)st + w * 96;
        for (int idx = l; idx < n4t; idx += 64) gt[idx] = lt[idx];

        int n4l = (ntw * 2) >> 2;
        float4*       gl = (float4*)(out + V_ELEMS + TRI_ELEMS + (size_t)g0 * 2) + (size_t)w * 32;
        const float4* ll = (const float4*)sl + w * 32;
        for (int idx = l; idx < n4l; idx += 64) gl[idx] = ll[idx];
    }
}

extern "C" void kernel_launch(void* const* d_in, const int* in_sizes, int n_in,
                              void* d_out, int out_size, void* d_ws, size_t ws_size,
                              hipStream_t stream) {
    const float* level = (const float*)d_in[0];
    float* out = (float*)d_out;
    int blocks = (NTET + TPB - 1) / TPB;
    mc_kernel<<<blocks, TPB, 0, stream>>>(level, out);
}